// Round 1
// 895.559 us; speedup vs baseline: 1.0254x; 1.0254x over previous
//
#include <hip/hip_runtime.h>

// Integrate-and-fire SNN input layer.
//   per t: m += image[t]; spk = (m >= 1.0f); m -= spk
// Outputs (concatenated in d_out, float32): spikes [T, N] (0/1), mempot [N].
// Pure streaming: ~1.06 GB mandatory HBM traffic -> kernel roofline ~168 us
// @ 6.3 TB/s. Harness poison-fills (~690 us) dominate dur_us; kernel is the
// only controllable part.
//
// R4: 8 neurons/thread (2 x vf4), 2048 blocks x 256 thr = exactly 32 waves/CU
// -> single occupancy pass (no block-relaunch seam). Pointer-bump addressing.
// Unroll 2 keeps VGPR <= 64 so __launch_bounds__(256,8) pins 8 waves/SIMD.

constexpr int TSTEPS = 32;
constexpr int N_NEU  = 4194304;

typedef float vf4 __attribute__((ext_vector_type(4)));

__global__ __launch_bounds__(256, 8) void snn_if_kernel(
    const float* __restrict__ image,      // [T, N]
    const float* __restrict__ mempot_in,  // [N]
    float* __restrict__ spikes,           // [T, N] out
    float* __restrict__ mempot_out)       // [N] out
{
    const size_t i = ((size_t)blockIdx.x * 256 + threadIdx.x) * 8;  // 8 neurons/thread

    vf4 m0 = __builtin_nontemporal_load(
        reinterpret_cast<const vf4*>(mempot_in + i));
    vf4 m1 = __builtin_nontemporal_load(
        reinterpret_cast<const vf4*>(mempot_in + i + 4));

    const float* ip = image + i;
    float*       sp = spikes + i;

#pragma unroll 2
    for (int t = 0; t < TSTEPS; ++t) {
        vf4 a = __builtin_nontemporal_load(reinterpret_cast<const vf4*>(ip));
        vf4 b = __builtin_nontemporal_load(reinterpret_cast<const vf4*>(ip + 4));
        vf4 s0, s1;

        m0.x += a.x; s0.x = (m0.x >= 1.0f) ? 1.0f : 0.0f; m0.x -= s0.x;
        m0.y += a.y; s0.y = (m0.y >= 1.0f) ? 1.0f : 0.0f; m0.y -= s0.y;
        m0.z += a.z; s0.z = (m0.z >= 1.0f) ? 1.0f : 0.0f; m0.z -= s0.z;
        m0.w += a.w; s0.w = (m0.w >= 1.0f) ? 1.0f : 0.0f; m0.w -= s0.w;

        m1.x += b.x; s1.x = (m1.x >= 1.0f) ? 1.0f : 0.0f; m1.x -= s1.x;
        m1.y += b.y; s1.y = (m1.y >= 1.0f) ? 1.0f : 0.0f; m1.y -= s1.y;
        m1.z += b.z; s1.z = (m1.z >= 1.0f) ? 1.0f : 0.0f; m1.z -= s1.z;
        m1.w += b.w; s1.w = (m1.w >= 1.0f) ? 1.0f : 0.0f; m1.w -= s1.w;

        __builtin_nontemporal_store(s0, reinterpret_cast<vf4*>(sp));
        __builtin_nontemporal_store(s1, reinterpret_cast<vf4*>(sp + 4));

        ip += N_NEU;
        sp += N_NEU;
    }

    __builtin_nontemporal_store(m0, reinterpret_cast<vf4*>(mempot_out + i));
    __builtin_nontemporal_store(m1, reinterpret_cast<vf4*>(mempot_out + i + 4));
}

extern "C" void kernel_launch(void* const* d_in, const int* in_sizes, int n_in,
                              void* d_out, int out_size, void* d_ws, size_t ws_size,
                              hipStream_t stream) {
    const float* image     = (const float*)d_in[0];   // [32, 4194304]
    const float* mempot_in = (const float*)d_in[1];   // [4194304]
    float* out = (float*)d_out;
    float* spikes     = out;                          // first T*N elements
    float* mempot_out = out + (size_t)TSTEPS * N_NEU; // last N elements

    const int threads = 256;
    const int blocks  = N_NEU / (8 * threads);        // 2048 blocks
    snn_if_kernel<<<blocks, threads, 0, stream>>>(image, mempot_in, spikes, mempot_out);
}